// Round 2
// baseline (4762.378 us; speedup 1.0000x reference)
//
#include <hip/hip_runtime.h>
#include <stdint.h>

#define NN 100000
#define NE 1600000

__global__ void deg_init(float* ns, float* nd, int n) {
    int i = blockIdx.x * blockDim.x + threadIdx.x;
    if (i < n) { ns[i] = 1.0f; nd[i] = 1.0f; }  // self-loop contributes 1 to both degrees
}

__global__ void deg_count(const int* __restrict__ src, const int* __restrict__ dst,
                          float* __restrict__ ns, float* __restrict__ nd, int e) {
    int i = blockIdx.x * blockDim.x + threadIdx.x;
    if (i < e) {
        atomicAdd(&ns[src[i]], 1.0f);
        atomicAdd(&nd[dst[i]], 1.0f);
    }
}

__global__ void deg_norm(float* ns, float* nd, int n) {
    int i = blockIdx.x * blockDim.x + threadIdx.x;
    if (i < n) {
        ns[i] = 1.0f / sqrtf(ns[i]);   // deg >= 1 always (self-loop)
        nd[i] = 1.0f / sqrtf(nd[i]);
    }
}

// C[r][c] = (sum_k X[r][k] * W[k][c]) * rowscale[r];  K fixed at 128.
// One row per wave; W staged to LDS; x-row broadcast via shuffles.
// Writes result to BOTH xw and agg (agg init = self-loop contribution).
template<int FOUT>
__global__ __launch_bounds__(256) void gemm_rows(const float* __restrict__ X,
        const float* __restrict__ W, const float* __restrict__ rowscale,
        float* __restrict__ xw, float* __restrict__ agg, int n)
{
    __shared__ float Wl[128 * FOUT];
    for (int i = threadIdx.x; i < 128 * FOUT; i += 256) Wl[i] = W[i];
    __syncthreads();
    const int lane = threadIdx.x & 63;
    int wave = blockIdx.x * 4 + (threadIdx.x >> 6);
    int nw = gridDim.x * 4;
    for (int r = wave; r < n; r += nw) {
        float2 xp = *(const float2*)(X + (size_t)r * 128 + 2 * lane);
        float acc0 = 0.f, acc1 = 0.f;
        #pragma unroll 16
        for (int k = 0; k < 128; ++k) {
            float xs = (k & 1) ? xp.y : xp.x;
            float xk = __shfl(xs, k >> 1, 64);
            if (FOUT == 128) {
                acc0 = fmaf(xk, Wl[k * 128 + lane], acc0);       // bank = lane%32: conflict-free
                acc1 = fmaf(xk, Wl[k * 128 + 64 + lane], acc1);
            } else {
                acc0 = fmaf(xk, Wl[k * 64 + lane], acc0);
            }
        }
        float s = rowscale ? rowscale[r] : 1.0f;
        if (FOUT == 128) {
            float v0 = acc0 * s, v1 = acc1 * s;
            size_t o = (size_t)r * 128;
            xw[o + lane] = v0; xw[o + 64 + lane] = v1;
            agg[o + lane] = v0; agg[o + 64 + lane] = v1;
        } else {
            float v0 = acc0 * s;
            size_t o = (size_t)r * 64;
            xw[o + lane] = v0; agg[o + lane] = v0;
        }
    }
}

// agg[dst[e]][:] += xw[src[e]][:], FOUT/4 threads per edge, float4 gather + scalar atomics
template<int FOUT>
__global__ __launch_bounds__(256) void scatter_edges(const int* __restrict__ src,
        const int* __restrict__ dst, const float* __restrict__ xw,
        float* __restrict__ agg, int e)
{
    const int TPE = FOUT / 4;
    int t = blockIdx.x * blockDim.x + threadIdx.x;
    int ed = t / TPE;
    if (ed >= e) return;
    int f = (t % TPE) * 4;
    int s = src[ed], d = dst[ed];
    float4 v = *(const float4*)(xw + (size_t)s * FOUT + f);
    float* ap = agg + (size_t)d * FOUT + f;
    atomicAdd(ap + 0, v.x);
    atomicAdd(ap + 1, v.y);
    atomicAdd(ap + 2, v.z);
    atomicAdd(ap + 3, v.w);
}

// h = relu(agg * nd[r] + b[c]) * ns[r]   (ns factor pre-applied for layer-2 GEMM)
__global__ void relu_scale(const float* __restrict__ agg, const float* __restrict__ nd,
        const float* __restrict__ ns, const float* __restrict__ b,
        float* __restrict__ h, int total)
{
    int i = blockIdx.x * blockDim.x + threadIdx.x;
    if (i < total) {
        int r = i >> 7, c = i & 127;
        float v = agg[i] * nd[r] + b[c];
        h[i] = fmaxf(v, 0.f) * ns[r];
    }
}

__global__ void final_out(const float* __restrict__ agg, const float* __restrict__ nd,
        const float* __restrict__ b, float* __restrict__ out, int total)
{
    int i = blockIdx.x * blockDim.x + threadIdx.x;
    if (i < total) {
        int r = i >> 6, c = i & 63;
        out[i] = agg[i] * nd[r] + b[c];
    }
}

extern "C" void kernel_launch(void* const* d_in, const int* in_sizes, int n_in,
                              void* d_out, int out_size, void* d_ws, size_t ws_size,
                              hipStream_t stream)
{
    const float* x  = (const float*)d_in[0];   // [N,128] f32
    const int* src  = (const int*)d_in[1];     // [E]
    const int* dst  = (const int*)d_in[2];     // [E]
    const float* W1 = (const float*)d_in[3];   // [128,128] f32
    const float* b1 = (const float*)d_in[4];   // [128] f32
    const float* W2 = (const float*)d_in[5];   // [128,64] f32
    const float* b2 = (const float*)d_in[6];   // [64] f32
    float* out = (float*)d_out;                // [N,64] f32

    const int n = NN, e = NE;

    // workspace layout (f32): ns[N] | nd[N] | bufA[128N] (xw1 -> h) | bufB[128N] (agg1 -> xw2|agg2)
    float* ns   = (float*)d_ws;
    float* nd   = ns + n;
    float* bufA = nd + n;
    float* bufB = bufA + (size_t)128 * n;

    deg_init<<<(n + 255) / 256, 256, 0, stream>>>(ns, nd, n);
    deg_count<<<(e + 255) / 256, 256, 0, stream>>>(src, dst, ns, nd, e);
    deg_norm<<<(n + 255) / 256, 256, 0, stream>>>(ns, nd, n);

    // layer 1: xw1 = (x @ W1) * ns   (row-scale commutes with right-multiply)
    gemm_rows<128><<<2048, 256, 0, stream>>>(x, W1, ns, bufA, bufB, n);
    scatter_edges<128><<<(e * 32 + 255) / 256, 256, 0, stream>>>(src, dst, bufA, bufB, e);
    relu_scale<<<(n * 128 + 255) / 256, 256, 0, stream>>>(bufB, nd, ns, b1, bufA, n * 128);

    // layer 2: h already carries ns factor
    float* xw2  = bufB;
    float* agg2 = bufB + (size_t)64 * n;
    gemm_rows<64><<<2048, 256, 0, stream>>>(bufA, W2, (const float*)nullptr, xw2, agg2, n);
    scatter_edges<64><<<(e * 16 + 255) / 256, 256, 0, stream>>>(src, dst, xw2, agg2, e);
    final_out<<<(n * 64 + 255) / 256, 256, 0, stream>>>(agg2, nd, b2, out, n * 64);
}

// Round 3
// 993.248 us; speedup vs baseline: 4.7948x; 4.7948x over previous
//
#include <hip/hip_runtime.h>
#include <stdint.h>

#define NN 100000
#define NE 1600000
#define SCAN_B 256
#define NB ((NN + SCAN_B - 1) / SCAN_B)   // 391

// ---------- degree / CSR build ----------

__global__ void deg_init(float* ns, int* in_cnt, int n) {
    int i = blockIdx.x * blockDim.x + threadIdx.x;
    if (i < n) { ns[i] = 1.0f; in_cnt[i] = 0; }   // self-loop pre-counted in ns
}

__global__ void deg_count(const int* __restrict__ src, const int* __restrict__ dst,
                          float* __restrict__ ns, int* __restrict__ in_cnt, int e) {
    int i = blockIdx.x * blockDim.x + threadIdx.x;
    if (i < e) {
        atomicAdd(&ns[src[i]], 1.0f);
        atomicAdd(&in_cnt[dst[i]], 1);
    }
}

// per-block exclusive scan of in_cnt -> row_ptr (block-local), block totals -> bsum
__global__ __launch_bounds__(SCAN_B) void scan_block(const int* __restrict__ in_cnt,
        int* __restrict__ row_ptr, int* __restrict__ bsum, int n) {
    __shared__ int sh[SCAN_B];
    int i = blockIdx.x * SCAN_B + threadIdx.x;
    int v = (i < n) ? in_cnt[i] : 0;
    sh[threadIdx.x] = v;
    __syncthreads();
    for (int off = 1; off < SCAN_B; off <<= 1) {
        int t = (threadIdx.x >= off) ? sh[threadIdx.x - off] : 0;
        __syncthreads();
        sh[threadIdx.x] += t;
        __syncthreads();
    }
    if (i < n) row_ptr[i] = sh[threadIdx.x] - v;           // exclusive
    if (threadIdx.x == SCAN_B - 1) bsum[blockIdx.x] = sh[SCAN_B - 1];
}

// single-block exclusive scan of the NB block sums
__global__ __launch_bounds__(512) void scan_bsum(const int* __restrict__ bsum,
        int* __restrict__ boff, int nb) {
    __shared__ int sh[512];
    int t = threadIdx.x;
    int v = (t < nb) ? bsum[t] : 0;
    sh[t] = v;
    __syncthreads();
    for (int off = 1; off < 512; off <<= 1) {
        int tv = (t >= off) ? sh[t - off] : 0;
        __syncthreads();
        sh[t] += tv;
        __syncthreads();
    }
    if (t < nb) boff[t] = sh[t] - v;                        // exclusive
}

// finalize: global row_ptr, cursor (reuses in_cnt storage), nd, ns
__global__ __launch_bounds__(SCAN_B) void scan_finalize(int* __restrict__ row_ptr,
        const int* __restrict__ boff, int* __restrict__ in_cnt /*in: count, out: cursor*/,
        float* __restrict__ nd, float* __restrict__ ns, int n, int e) {
    int i = blockIdx.x * SCAN_B + threadIdx.x;
    if (i < n) {
        int c = in_cnt[i];
        nd[i] = rsqrtf((float)c + 1.0f);                    // +1 self-loop
        ns[i] = rsqrtf(ns[i]);                              // ns held out-degree incl. self
        int rp = row_ptr[i] + boff[blockIdx.x];
        row_ptr[i] = rp;
        in_cnt[i] = rp;                                     // cursor
    }
    if (i == 0) row_ptr[n] = e;
}

__global__ void place_edges(const int* __restrict__ src, const int* __restrict__ dst,
        int* __restrict__ cursor, int* __restrict__ csr, int e) {
    int i = blockIdx.x * blockDim.x + threadIdx.x;
    if (i < e) {
        int pos = atomicAdd(&cursor[dst[i]], 1);
        csr[pos] = src[i];
    }
}

// ---------- GEMM: C[r][c] = (sum_k X[r][k]*W[k][c]) * rowscale[r], K=128 ----------
// One row per wave; W staged in LDS (FOUT=128: packed so lane reads float2 = cols c,c+64).
template<int FOUT>
__global__ __launch_bounds__(256) void gemm_rows(const float* __restrict__ X,
        const float* __restrict__ W, const float* __restrict__ rowscale,
        float* __restrict__ xw, int n)
{
    __shared__ float Wl[128 * FOUT];
    if (FOUT == 128) {
        for (int i = threadIdx.x; i < 128 * 128; i += 256) {
            int k = i >> 7, col = i & 127;
            Wl[k * 128 + ((col & 63) << 1) + (col >> 6)] = W[i];
        }
    } else {
        for (int i = threadIdx.x; i < 128 * FOUT; i += 256) Wl[i] = W[i];
    }
    __syncthreads();
    const int lane = threadIdx.x & 63;
    int wave = blockIdx.x * 4 + (threadIdx.x >> 6);
    int nw = gridDim.x * 4;
    for (int r = wave; r < n; r += nw) {
        float2 xp = *(const float2*)(X + (size_t)r * 128 + 2 * lane);
        float acc0 = 0.f, acc1 = 0.f;
        #pragma unroll 16
        for (int k = 0; k < 128; ++k) {
            float xs = (k & 1) ? xp.y : xp.x;
            float xk = __shfl(xs, k >> 1, 64);
            if (FOUT == 128) {
                float2 wv = *(const float2*)(Wl + k * 128 + 2 * lane);   // ds_read_b64, 2-way (free)
                acc0 = fmaf(xk, wv.x, acc0);
                acc1 = fmaf(xk, wv.y, acc1);
            } else {
                acc0 = fmaf(xk, Wl[k * 64 + lane], acc0);
            }
        }
        float s = rowscale ? rowscale[r] : 1.0f;
        if (FOUT == 128) {
            size_t o = (size_t)r * 128;
            xw[o + lane] = acc0 * s;                 // col = lane
            xw[o + 64 + lane] = acc1 * s;            // col = lane+64
        } else {
            xw[(size_t)r * 64 + lane] = acc0 * s;
        }
    }
}

// ---------- CSR gather-aggregate + fused epilogue ----------
// out[r] = epi( (xw[r] + sum_{s in N(r)} xw[s]) * nd[r] + b )
// RELU: out = relu(.)*ns[r]   (layer 1);  else plain (layer 2, final output)
template<int FOUT, bool RELU>
__global__ __launch_bounds__(256) void agg_csr(const int* __restrict__ row_ptr,
        const int* __restrict__ csr, const float* __restrict__ xw,
        const float* __restrict__ nd, const float* __restrict__ ns,
        const float* __restrict__ b, float* __restrict__ out, int n)
{
    int r = blockIdx.x * 4 + (threadIdx.x >> 6);
    if (r >= n) return;
    const int lane = threadIdx.x & 63;
    int beg = row_ptr[r], end = row_ptr[r + 1];
    if (FOUT == 128) {
        const float2* xp = (const float2*)xw;
        float2 acc = xp[(size_t)r * 64 + lane];              // self-loop
        int j = beg;
        for (; j + 2 <= end; j += 2) {
            int s0 = csr[j], s1 = csr[j + 1];
            float2 v0 = xp[(size_t)s0 * 64 + lane];
            float2 v1 = xp[(size_t)s1 * 64 + lane];
            acc.x += v0.x; acc.y += v0.y;
            acc.x += v1.x; acc.y += v1.y;
        }
        if (j < end) {
            float2 v0 = xp[(size_t)csr[j] * 64 + lane];
            acc.x += v0.x; acc.y += v0.y;
        }
        float ndr = nd[r];
        float o0 = acc.x * ndr + b[2 * lane];
        float o1 = acc.y * ndr + b[2 * lane + 1];
        if (RELU) {
            float nsr = ns[r];
            o0 = fmaxf(o0, 0.f) * nsr;
            o1 = fmaxf(o1, 0.f) * nsr;
        }
        ((float2*)out)[(size_t)r * 64 + lane] = make_float2(o0, o1);
    } else {
        float acc = xw[(size_t)r * 64 + lane];
        int j = beg;
        for (; j + 2 <= end; j += 2) {
            int s0 = csr[j], s1 = csr[j + 1];
            float v0 = xw[(size_t)s0 * 64 + lane];
            float v1 = xw[(size_t)s1 * 64 + lane];
            acc += v0; acc += v1;
        }
        if (j < end) acc += xw[(size_t)csr[j] * 64 + lane];
        float o0 = acc * nd[r] + b[lane];
        if (RELU) o0 = fmaxf(o0, 0.f) * ns[r];
        out[(size_t)r * 64 + lane] = o0;
    }
}

extern "C" void kernel_launch(void* const* d_in, const int* in_sizes, int n_in,
                              void* d_out, int out_size, void* d_ws, size_t ws_size,
                              hipStream_t stream)
{
    const float* x  = (const float*)d_in[0];   // [N,128] f32
    const int* src  = (const int*)d_in[1];     // [E]
    const int* dst  = (const int*)d_in[2];     // [E]
    const float* W1 = (const float*)d_in[3];   // [128,128] f32
    const float* b1 = (const float*)d_in[4];   // [128] f32
    const float* W2 = (const float*)d_in[5];   // [128,64] f32
    const float* b2 = (const float*)d_in[6];   // [64] f32
    float* out = (float*)d_out;                // [N,64] f32

    const int n = NN, e = NE;

    // workspace layout
    char* p = (char*)d_ws;
    float* ns      = (float*)p; p += (size_t)n * 4;
    float* nd      = (float*)p; p += (size_t)n * 4;
    int*   in_cnt  = (int*)p;   p += (size_t)n * 4;          // becomes cursor
    int*   row_ptr = (int*)p;   p += (size_t)(n + 1) * 4;
    int*   bsum    = (int*)p;   p += (size_t)NB * 4;
    int*   boff    = (int*)p;   p += (size_t)NB * 4;
    int*   csr     = (int*)p;   p += (size_t)e * 4;
    p = (char*)(((uintptr_t)p + 255) & ~(uintptr_t)255);
    float* bufA    = (float*)p; p += (size_t)128 * n * 4;    // xw1, then xw2
    float* bufB    = (float*)p;                              // h

    deg_init<<<(n + 255) / 256, 256, 0, stream>>>(ns, in_cnt, n);
    deg_count<<<(e + 255) / 256, 256, 0, stream>>>(src, dst, ns, in_cnt, e);
    scan_block<<<NB, SCAN_B, 0, stream>>>(in_cnt, row_ptr, bsum, n);
    scan_bsum<<<1, 512, 0, stream>>>(bsum, boff, NB);
    scan_finalize<<<NB, SCAN_B, 0, stream>>>(row_ptr, boff, in_cnt, nd, ns, n, e);
    place_edges<<<(e + 255) / 256, 256, 0, stream>>>(src, dst, in_cnt, csr, e);

    // layer 1: xw1 = (x @ W1) * ns ; h = relu((xw1[r]+sum nbr)*nd + b1) * ns
    gemm_rows<128><<<2048, 256, 0, stream>>>(x, W1, ns, bufA, n);
    agg_csr<128, true><<<n / 4, 256, 0, stream>>>(row_ptr, csr, bufA, nd, ns, b1, bufB, n);

    // layer 2: xw2 = h @ W2 ; out = (xw2[r]+sum nbr)*nd + b2
    gemm_rows<64><<<2048, 256, 0, stream>>>(bufB, W2, (const float*)nullptr, bufA, n);
    agg_csr<64, false><<<n / 4, 256, 0, stream>>>(row_ptr, csr, bufA, nd, ns, b2, out, n);
}

// Round 4
// 646.342 us; speedup vs baseline: 7.3682x; 1.5367x over previous
//
#include <hip/hip_runtime.h>
#include <stdint.h>

#define NN 100000
#define NE 1600000
#define SCAN_B 256
#define NB ((NN + SCAN_B - 1) / SCAN_B)   // 391

typedef __attribute__((ext_vector_type(8))) __bf16 bf16x8;
typedef __attribute__((ext_vector_type(4))) float  f32x4;

// ---------- degree / CSR build ----------

__global__ void deg_init(float* ns, int* in_cnt, int n) {
    int i = blockIdx.x * blockDim.x + threadIdx.x;
    if (i < n) { ns[i] = 1.0f; in_cnt[i] = 0; }   // self-loop pre-counted in ns
}

__global__ void deg_count(const int* __restrict__ src, const int* __restrict__ dst,
                          float* __restrict__ ns, int* __restrict__ in_cnt, int e) {
    int i = blockIdx.x * blockDim.x + threadIdx.x;
    if (i < e) {
        atomicAdd(&ns[src[i]], 1.0f);
        atomicAdd(&in_cnt[dst[i]], 1);
    }
}

__global__ __launch_bounds__(SCAN_B) void scan_block(const int* __restrict__ in_cnt,
        int* __restrict__ row_ptr, int* __restrict__ bsum, int n) {
    __shared__ int sh[SCAN_B];
    int i = blockIdx.x * SCAN_B + threadIdx.x;
    int v = (i < n) ? in_cnt[i] : 0;
    sh[threadIdx.x] = v;
    __syncthreads();
    for (int off = 1; off < SCAN_B; off <<= 1) {
        int t = (threadIdx.x >= off) ? sh[threadIdx.x - off] : 0;
        __syncthreads();
        sh[threadIdx.x] += t;
        __syncthreads();
    }
    if (i < n) row_ptr[i] = sh[threadIdx.x] - v;           // exclusive
    if (threadIdx.x == SCAN_B - 1) bsum[blockIdx.x] = sh[SCAN_B - 1];
}

__global__ __launch_bounds__(512) void scan_bsum(const int* __restrict__ bsum,
        int* __restrict__ boff, int nb) {
    __shared__ int sh[512];
    int t = threadIdx.x;
    int v = (t < nb) ? bsum[t] : 0;
    sh[t] = v;
    __syncthreads();
    for (int off = 1; off < 512; off <<= 1) {
        int tv = (t >= off) ? sh[t - off] : 0;
        __syncthreads();
        sh[t] += tv;
        __syncthreads();
    }
    if (t < nb) boff[t] = sh[t] - v;                        // exclusive
}

__global__ __launch_bounds__(SCAN_B) void scan_finalize(int* __restrict__ row_ptr,
        const int* __restrict__ boff, int* __restrict__ in_cnt /*in: count, out: cursor*/,
        float* __restrict__ nd, float* __restrict__ ns, int n, int e) {
    int i = blockIdx.x * SCAN_B + threadIdx.x;
    if (i < n) {
        int c = in_cnt[i];
        nd[i] = rsqrtf((float)c + 1.0f);                    // +1 self-loop
        ns[i] = rsqrtf(ns[i]);                              // out-degree incl. self
        int rp = row_ptr[i] + boff[blockIdx.x];
        row_ptr[i] = rp;
        in_cnt[i] = rp;                                     // cursor
    }
    if (i == 0) row_ptr[n] = e;
}

__global__ void place_edges(const int* __restrict__ src, const int* __restrict__ dst,
        int* __restrict__ cursor, int* __restrict__ csr, int e) {
    int i = blockIdx.x * blockDim.x + threadIdx.x;
    if (i < e) {
        int pos = atomicAdd(&cursor[dst[i]], 1);
        csr[pos] = src[i];
    }
}

// ---------- MFMA GEMM via split-bf16: X@W ~= Xhi@Whi + Xlo@Whi + Xhi@Wlo ----------
// X [N,128] f32, W [128,F] f32, out xw [N,F] f32 (optionally * rowscale[r]).
// One wave computes a 16-row x F tile; K=128 in 4 chunks of 32.
// W staged in LDS as hi/lo bf16 planes, pre-permuted into B-fragment order:
//   index ((cb*4 + kc)*64 + lane)*8 + j  ->  W[kc*32 + (lane>>4)*8 + j][cb*16 + (lane&15)]
// so each lane's 8 k-values are contiguous: one conflict-free ds_read_b128.
template<int F, bool SCALE>
__global__ __launch_bounds__(256) void gemm_mfma(const float* __restrict__ X,
        const float* __restrict__ W, const float* __restrict__ rowscale,
        float* __restrict__ xw, int nchunks)
{
    __shared__ __bf16 Whi[(F/16)*4*64*8];
    __shared__ __bf16 Wlo[(F/16)*4*64*8];
    for (int idx = threadIdx.x; idx < (F/16)*4*64; idx += 256) {
        int cb = idx >> 8;                  // idx / 256
        int kc = (idx >> 6) & 3;
        int ln = idx & 63;
        int col = cb*16 + (ln & 15);
        int kb  = kc*32 + (ln >> 4)*8;
        #pragma unroll
        for (int j = 0; j < 8; ++j) {
            float f = W[(size_t)(kb + j)*F + col];
            __bf16 h = (__bf16)f;
            Whi[idx*8 + j] = h;
            Wlo[idx*8 + j] = (__bf16)(f - (float)h);
        }
    }
    __syncthreads();
    const int lane = threadIdx.x & 63;
    const int m = lane & 15, q = lane >> 4;
    int wchunk = blockIdx.x*4 + (threadIdx.x >> 6);
    int stride = gridDim.x*4;
    for (int c = wchunk; c < nchunks; c += stride) {
        int rbase = c*16;
        const float* xrow = X + (size_t)(rbase + m)*128;
        f32x4 acc[F/16];
        #pragma unroll
        for (int i = 0; i < F/16; ++i) acc[i] = (f32x4)0.f;
        #pragma unroll
        for (int kc = 0; kc < 4; ++kc) {
            int kb = kc*32 + q*8;
            float4 v0 = *(const float4*)(xrow + kb);
            float4 v1 = *(const float4*)(xrow + kb + 4);
            float xf[8] = {v0.x, v0.y, v0.z, v0.w, v1.x, v1.y, v1.z, v1.w};
            bf16x8 ahi, alo;
            #pragma unroll
            for (int j = 0; j < 8; ++j) {
                __bf16 h = (__bf16)xf[j];
                ahi[j] = h;
                alo[j] = (__bf16)(xf[j] - (float)h);
            }
            #pragma unroll
            for (int cb = 0; cb < F/16; ++cb) {
                bf16x8 bh = *(const bf16x8*)(Whi + ((cb*4 + kc)*64 + lane)*8);
                bf16x8 bl = *(const bf16x8*)(Wlo + ((cb*4 + kc)*64 + lane)*8);
                acc[cb] = __builtin_amdgcn_mfma_f32_16x16x32_bf16(ahi, bh, acc[cb], 0, 0, 0);
                acc[cb] = __builtin_amdgcn_mfma_f32_16x16x32_bf16(alo, bh, acc[cb], 0, 0, 0);
                acc[cb] = __builtin_amdgcn_mfma_f32_16x16x32_bf16(ahi, bl, acc[cb], 0, 0, 0);
            }
        }
        // C/D layout: col = cb*16 + (lane&15), row = rbase + (lane>>4)*4 + reg
        float s[4];
        #pragma unroll
        for (int reg = 0; reg < 4; ++reg)
            s[reg] = SCALE ? rowscale[rbase + q*4 + reg] : 1.0f;
        #pragma unroll
        for (int cb = 0; cb < F/16; ++cb)
            #pragma unroll
            for (int reg = 0; reg < 4; ++reg)
                xw[(size_t)(rbase + q*4 + reg)*F + cb*16 + m] = acc[cb][reg] * s[reg];
    }
}

// ---------- CSR gather-aggregate + fused epilogue ----------
template<int FOUT, bool RELU>
__global__ __launch_bounds__(256) void agg_csr(const int* __restrict__ row_ptr,
        const int* __restrict__ csr, const float* __restrict__ xw,
        const float* __restrict__ nd, const float* __restrict__ ns,
        const float* __restrict__ b, float* __restrict__ out, int n)
{
    int r = blockIdx.x * 4 + (threadIdx.x >> 6);
    if (r >= n) return;
    const int lane = threadIdx.x & 63;
    int beg = row_ptr[r], end = row_ptr[r + 1];
    if (FOUT == 128) {
        const float2* xp = (const float2*)xw;
        float2 acc = xp[(size_t)r * 64 + lane];              // self-loop
        int j = beg;
        for (; j + 2 <= end; j += 2) {
            int s0 = csr[j], s1 = csr[j + 1];
            float2 v0 = xp[(size_t)s0 * 64 + lane];
            float2 v1 = xp[(size_t)s1 * 64 + lane];
            acc.x += v0.x; acc.y += v0.y;
            acc.x += v1.x; acc.y += v1.y;
        }
        if (j < end) {
            float2 v0 = xp[(size_t)csr[j] * 64 + lane];
            acc.x += v0.x; acc.y += v0.y;
        }
        float ndr = nd[r];
        float o0 = acc.x * ndr + b[2 * lane];
        float o1 = acc.y * ndr + b[2 * lane + 1];
        if (RELU) {
            float nsr = ns[r];
            o0 = fmaxf(o0, 0.f) * nsr;
            o1 = fmaxf(o1, 0.f) * nsr;
        }
        ((float2*)out)[(size_t)r * 64 + lane] = make_float2(o0, o1);
    } else {
        float acc = xw[(size_t)r * 64 + lane];
        int j = beg;
        for (; j + 2 <= end; j += 2) {
            int s0 = csr[j], s1 = csr[j + 1];
            acc += xw[(size_t)s0 * 64 + lane];
            acc += xw[(size_t)s1 * 64 + lane];
        }
        if (j < end) acc += xw[(size_t)csr[j] * 64 + lane];
        float o0 = acc * nd[r] + b[lane];
        if (RELU) o0 = fmaxf(o0, 0.f) * ns[r];
        out[(size_t)r * 64 + lane] = o0;
    }
}

extern "C" void kernel_launch(void* const* d_in, const int* in_sizes, int n_in,
                              void* d_out, int out_size, void* d_ws, size_t ws_size,
                              hipStream_t stream)
{
    const float* x  = (const float*)d_in[0];   // [N,128] f32
    const int* src  = (const int*)d_in[1];     // [E]
    const int* dst  = (const int*)d_in[2];     // [E]
    const float* W1 = (const float*)d_in[3];   // [128,128] f32
    const float* b1 = (const float*)d_in[4];   // [128] f32
    const float* W2 = (const float*)d_in[5];   // [128,64] f32
    const float* b2 = (const float*)d_in[6];   // [64] f32
    float* out = (float*)d_out;                // [N,64] f32

    const int n = NN, e = NE;
    const int nchunks = n / 16;                // 6250, exact

    // workspace layout
    char* p = (char*)d_ws;
    float* ns      = (float*)p; p += (size_t)n * 4;
    float* nd      = (float*)p; p += (size_t)n * 4;
    int*   in_cnt  = (int*)p;   p += (size_t)n * 4;          // becomes cursor
    int*   row_ptr = (int*)p;   p += (size_t)(n + 1) * 4;
    int*   bsum    = (int*)p;   p += (size_t)NB * 4;
    int*   boff    = (int*)p;   p += (size_t)NB * 4;
    int*   csr     = (int*)p;   p += (size_t)e * 4;
    p = (char*)(((uintptr_t)p + 255) & ~(uintptr_t)255);
    float* bufA    = (float*)p; p += (size_t)128 * n * 4;    // xw1, then xw2
    float* bufB    = (float*)p;                              // h

    deg_init<<<(n + 255) / 256, 256, 0, stream>>>(ns, in_cnt, n);
    deg_count<<<(e + 255) / 256, 256, 0, stream>>>(src, dst, ns, in_cnt, e);
    scan_block<<<NB, SCAN_B, 0, stream>>>(in_cnt, row_ptr, bsum, n);
    scan_bsum<<<1, 512, 0, stream>>>(bsum, boff, NB);
    scan_finalize<<<NB, SCAN_B, 0, stream>>>(row_ptr, boff, in_cnt, nd, ns, n, e);
    place_edges<<<(e + 255) / 256, 256, 0, stream>>>(src, dst, in_cnt, csr, e);

    // layer 1: xw1 = (x @ W1) * ns ; h = relu((xw1[r]+sum nbr)*nd + b1) * ns
    gemm_mfma<128, true><<<1024, 256, 0, stream>>>(x, W1, ns, bufA, nchunks);
    agg_csr<128, true><<<n / 4, 256, 0, stream>>>(row_ptr, csr, bufA, nd, ns, b1, bufB, n);

    // layer 2: xw2 = h @ W2 ; out = (xw2[r]+sum nbr)*nd + b2
    gemm_mfma<64, false><<<1024, 256, 0, stream>>>(bufB, W2, (const float*)nullptr, bufA, nchunks);
    agg_csr<64, false><<<n / 4, 256, 0, stream>>>(row_ptr, csr, bufA, nd, ns, b2, out, n);
}

// Round 5
// 473.271 us; speedup vs baseline: 10.0627x; 1.3657x over previous
//
#include <hip/hip_runtime.h>
#include <stdint.h>

#define NN 100000
#define NE 1600000
#define NBUCK 391            // ceil(NN/256)
#define CHUNK 4000
#define NPART (NE / CHUNK)   // 400, exact

typedef __attribute__((ext_vector_type(8))) __bf16 bf16x8;
typedef __attribute__((ext_vector_type(4))) float  f32x4;

// ---------- CSR build: two-level LDS-histogram partition (no per-edge global atomics) ----------

__global__ void zero_ints(int* p, int n) {
    int i = blockIdx.x * blockDim.x + threadIdx.x;
    if (i < n) p[i] = 0;
}

// per-block LDS histograms of dst>>8 and src>>8; one global atomic per (block,bin)
__global__ __launch_bounds__(256) void coarse_hist(const int* __restrict__ src,
        const int* __restrict__ dst, int* __restrict__ cd, int* __restrict__ cs, int e)
{
    __shared__ int hd[NBUCK], hs[NBUCK];
    for (int t = threadIdx.x; t < NBUCK; t += 256) { hd[t] = 0; hs[t] = 0; }
    __syncthreads();
    for (int i = blockIdx.x * 256 + threadIdx.x; i < e; i += gridDim.x * 256) {
        atomicAdd(&hd[dst[i] >> 8], 1);
        atomicAdd(&hs[src[i] >> 8], 1);
    }
    __syncthreads();
    for (int t = threadIdx.x; t < NBUCK; t += 256) {
        if (hd[t]) atomicAdd(&cd[t], hd[t]);
        if (hs[t]) atomicAdd(&cs[t], hs[t]);
    }
}

// single-block exclusive scans of cd, cs -> offsets + cursors; also row_ptr[n]=e
__global__ __launch_bounds__(512) void scan_coarse(const int* __restrict__ cd,
        const int* __restrict__ cs, int* __restrict__ offd, int* __restrict__ offs,
        int* __restrict__ curd, int* __restrict__ curs, int* __restrict__ row_ptr,
        int n, int e)
{
    __shared__ int sh[512];
    int t = threadIdx.x;
    int v = (t < NBUCK) ? cd[t] : 0;
    sh[t] = v;
    __syncthreads();
    for (int o = 1; o < 512; o <<= 1) {
        int tv = (t >= o) ? sh[t - o] : 0;
        __syncthreads();
        sh[t] += tv;
        __syncthreads();
    }
    if (t < NBUCK) { int ex = sh[t] - v; offd[t] = ex; curd[t] = ex; }
    if (t == 0) { offd[NBUCK] = e; row_ptr[n] = e; }
    __syncthreads();
    v = (t < NBUCK) ? cs[t] : 0;
    sh[t] = v;
    __syncthreads();
    for (int o = 1; o < 512; o <<= 1) {
        int tv = (t >= o) ? sh[t - o] : 0;
        __syncthreads();
        sh[t] += tv;
        __syncthreads();
    }
    if (t < NBUCK) { int ex = sh[t] - v; offs[t] = ex; curs[t] = ex; }
    if (t == 0) offs[NBUCK] = e;
}

// partition (src,dst) pairs into coarse buckets by dst>>8; one reserve-atomic per (block,bin)
__global__ __launch_bounds__(256) void part_dst(const int* __restrict__ src,
        const int* __restrict__ dst, int* __restrict__ curd, int2* __restrict__ pairs, int e)
{
    __shared__ int h[NBUCK];
    __shared__ int base[NBUCK];
    int beg = blockIdx.x * CHUNK;
    int end = beg + CHUNK; if (end > e) end = e;
    for (int t = threadIdx.x; t < NBUCK; t += 256) h[t] = 0;
    __syncthreads();
    for (int i = beg + threadIdx.x; i < end; i += 256)
        atomicAdd(&h[dst[i] >> 8], 1);
    __syncthreads();
    for (int t = threadIdx.x; t < NBUCK; t += 256)
        base[t] = h[t] ? atomicAdd(&curd[t], h[t]) : 0;
    __syncthreads();
    for (int i = beg + threadIdx.x; i < end; i += 256) {
        int d = dst[i];
        int pos = atomicAdd(&base[d >> 8], 1);     // LDS atomic
        pairs[pos] = make_int2(src[i], d);
    }
}

// partition src values into coarse buckets by src>>8 (counting only downstream)
__global__ __launch_bounds__(256) void part_src(const int* __restrict__ src,
        int* __restrict__ curs, int* __restrict__ bsrc, int e)
{
    __shared__ int h[NBUCK];
    __shared__ int base[NBUCK];
    int beg = blockIdx.x * CHUNK;
    int end = beg + CHUNK; if (end > e) end = e;
    for (int t = threadIdx.x; t < NBUCK; t += 256) h[t] = 0;
    __syncthreads();
    for (int i = beg + threadIdx.x; i < end; i += 256)
        atomicAdd(&h[src[i] >> 8], 1);
    __syncthreads();
    for (int t = threadIdx.x; t < NBUCK; t += 256)
        base[t] = h[t] ? atomicAdd(&curs[t], h[t]) : 0;
    __syncthreads();
    for (int i = beg + threadIdx.x; i < end; i += 256) {
        int s = src[i];
        int pos = atomicAdd(&base[s >> 8], 1);     // LDS atomic
        bsrc[pos] = s;
    }
}

// one block per bucket: fine 256-bin histogram + scan -> row_ptr, nd, CSR placement (LDS atomics only)
__global__ __launch_bounds__(256) void fine_dst(const int* __restrict__ offd,
        const int2* __restrict__ pairs, int* __restrict__ row_ptr,
        float* __restrict__ nd, int* __restrict__ csr, int n)
{
    __shared__ int h[256], sh[256], cur[256];
    int b = blockIdx.x;
    int beg = offd[b], end = offd[b + 1];
    int t = threadIdx.x;
    h[t] = 0;
    __syncthreads();
    for (int i = beg + t; i < end; i += 256)
        atomicAdd(&h[pairs[i].y & 255], 1);
    __syncthreads();
    int v = h[t];
    sh[t] = v;
    __syncthreads();
    for (int o = 1; o < 256; o <<= 1) {
        int tv = (t >= o) ? sh[t - o] : 0;
        __syncthreads();
        sh[t] += tv;
        __syncthreads();
    }
    int ex = sh[t] - v;
    int node = (b << 8) + t;
    if (node < n) {
        row_ptr[node] = beg + ex;
        nd[node] = rsqrtf((float)v + 1.0f);        // +1 self-loop
    }
    cur[t] = beg + ex;
    __syncthreads();
    for (int i = beg + t; i < end; i += 256) {
        int2 pr = pairs[i];
        int pos = atomicAdd(&cur[pr.y & 255], 1);  // LDS atomic
        csr[pos] = pr.x;
    }
}

// one block per bucket: count src occurrences -> ns (out-degree incl. self-loop)
__global__ __launch_bounds__(256) void fine_src(const int* __restrict__ offs,
        const int* __restrict__ bsrc, float* __restrict__ ns, int n)
{
    __shared__ int h[256];
    int b = blockIdx.x;
    int beg = offs[b], end = offs[b + 1];
    int t = threadIdx.x;
    h[t] = 0;
    __syncthreads();
    for (int i = beg + t; i < end; i += 256)
        atomicAdd(&h[bsrc[i] & 255], 1);
    __syncthreads();
    int node = (b << 8) + t;
    if (node < n) ns[node] = rsqrtf((float)h[t] + 1.0f);
}

// ---------- MFMA GEMM via split-bf16: X@W ~= Xhi@Whi + Xlo@Whi + Xhi@Wlo ----------
template<int F, bool SCALE>
__global__ __launch_bounds__(256) void gemm_mfma(const float* __restrict__ X,
        const float* __restrict__ W, const float* __restrict__ rowscale,
        float* __restrict__ xw, int nchunks)
{
    __shared__ __bf16 Whi[(F/16)*4*64*8];
    __shared__ __bf16 Wlo[(F/16)*4*64*8];
    for (int idx = threadIdx.x; idx < (F/16)*4*64; idx += 256) {
        int cb = idx >> 8;
        int kc = (idx >> 6) & 3;
        int ln = idx & 63;
        int col = cb*16 + (ln & 15);
        int kb  = kc*32 + (ln >> 4)*8;
        #pragma unroll
        for (int j = 0; j < 8; ++j) {
            float f = W[(size_t)(kb + j)*F + col];
            __bf16 h = (__bf16)f;
            Whi[idx*8 + j] = h;
            Wlo[idx*8 + j] = (__bf16)(f - (float)h);
        }
    }
    __syncthreads();
    const int lane = threadIdx.x & 63;
    const int m = lane & 15, q = lane >> 4;
    int wchunk = blockIdx.x*4 + (threadIdx.x >> 6);
    int stride = gridDim.x*4;
    for (int c = wchunk; c < nchunks; c += stride) {
        int rbase = c*16;
        const float* xrow = X + (size_t)(rbase + m)*128;
        f32x4 acc[F/16];
        #pragma unroll
        for (int i = 0; i < F/16; ++i) acc[i] = (f32x4)0.f;
        #pragma unroll
        for (int kc = 0; kc < 4; ++kc) {
            int kb = kc*32 + q*8;
            float4 v0 = *(const float4*)(xrow + kb);
            float4 v1 = *(const float4*)(xrow + kb + 4);
            float xf[8] = {v0.x, v0.y, v0.z, v0.w, v1.x, v1.y, v1.z, v1.w};
            bf16x8 ahi, alo;
            #pragma unroll
            for (int j = 0; j < 8; ++j) {
                __bf16 h = (__bf16)xf[j];
                ahi[j] = h;
                alo[j] = (__bf16)(xf[j] - (float)h);
            }
            #pragma unroll
            for (int cb = 0; cb < F/16; ++cb) {
                bf16x8 bh = *(const bf16x8*)(Whi + ((cb*4 + kc)*64 + lane)*8);
                bf16x8 bl = *(const bf16x8*)(Wlo + ((cb*4 + kc)*64 + lane)*8);
                acc[cb] = __builtin_amdgcn_mfma_f32_16x16x32_bf16(ahi, bh, acc[cb], 0, 0, 0);
                acc[cb] = __builtin_amdgcn_mfma_f32_16x16x32_bf16(alo, bh, acc[cb], 0, 0, 0);
                acc[cb] = __builtin_amdgcn_mfma_f32_16x16x32_bf16(ahi, bl, acc[cb], 0, 0, 0);
            }
        }
        float s[4];
        #pragma unroll
        for (int reg = 0; reg < 4; ++reg)
            s[reg] = SCALE ? rowscale[rbase + q*4 + reg] : 1.0f;
        #pragma unroll
        for (int cb = 0; cb < F/16; ++cb)
            #pragma unroll
            for (int reg = 0; reg < 4; ++reg)
                xw[(size_t)(rbase + q*4 + reg)*F + cb*16 + m] = acc[cb][reg] * s[reg];
    }
}

// ---------- CSR gather-aggregate + fused epilogue ----------
template<int FOUT, bool RELU>
__global__ __launch_bounds__(256) void agg_csr(const int* __restrict__ row_ptr,
        const int* __restrict__ csr, const float* __restrict__ xw,
        const float* __restrict__ nd, const float* __restrict__ ns,
        const float* __restrict__ b, float* __restrict__ out, int n)
{
    int r = blockIdx.x * 4 + (threadIdx.x >> 6);
    if (r >= n) return;
    const int lane = threadIdx.x & 63;
    int beg = row_ptr[r], end = row_ptr[r + 1];
    if (FOUT == 128) {
        const float2* xp = (const float2*)xw;
        float2 acc = xp[(size_t)r * 64 + lane];              // self-loop
        int j = beg;
        for (; j + 2 <= end; j += 2) {
            int s0 = csr[j], s1 = csr[j + 1];
            float2 v0 = xp[(size_t)s0 * 64 + lane];
            float2 v1 = xp[(size_t)s1 * 64 + lane];
            acc.x += v0.x; acc.y += v0.y;
            acc.x += v1.x; acc.y += v1.y;
        }
        if (j < end) {
            float2 v0 = xp[(size_t)csr[j] * 64 + lane];
            acc.x += v0.x; acc.y += v0.y;
        }
        float ndr = nd[r];
        float o0 = acc.x * ndr + b[2 * lane];
        float o1 = acc.y * ndr + b[2 * lane + 1];
        if (RELU) {
            float nsr = ns[r];
            o0 = fmaxf(o0, 0.f) * nsr;
            o1 = fmaxf(o1, 0.f) * nsr;
        }
        ((float2*)out)[(size_t)r * 64 + lane] = make_float2(o0, o1);
    } else {
        float acc = xw[(size_t)r * 64 + lane];
        int j = beg;
        for (; j + 2 <= end; j += 2) {
            int s0 = csr[j], s1 = csr[j + 1];
            acc += xw[(size_t)s0 * 64 + lane];
            acc += xw[(size_t)s1 * 64 + lane];
        }
        if (j < end) acc += xw[(size_t)csr[j] * 64 + lane];
        float o0 = acc * nd[r] + b[lane];
        if (RELU) o0 = fmaxf(o0, 0.f) * ns[r];
        out[(size_t)r * 64 + lane] = o0;
    }
}

extern "C" void kernel_launch(void* const* d_in, const int* in_sizes, int n_in,
                              void* d_out, int out_size, void* d_ws, size_t ws_size,
                              hipStream_t stream)
{
    const float* x  = (const float*)d_in[0];   // [N,128] f32
    const int* src  = (const int*)d_in[1];     // [E]
    const int* dst  = (const int*)d_in[2];     // [E]
    const float* W1 = (const float*)d_in[3];   // [128,128] f32
    const float* b1 = (const float*)d_in[4];   // [128] f32
    const float* W2 = (const float*)d_in[5];   // [128,64] f32
    const float* b2 = (const float*)d_in[6];   // [64] f32
    float* out = (float*)d_out;                // [N,64] f32

    const int n = NN, e = NE;
    const int nchunks = n / 16;                // 6250, exact

    // workspace layout
    char* p = (char*)d_ws;
    float* ns      = (float*)p; p += (size_t)n * 4;
    float* nd      = (float*)p; p += (size_t)n * 4;
    int*   row_ptr = (int*)p;   p += (size_t)(n + 1) * 4;
    int*   cd      = (int*)p;   p += (size_t)NBUCK * 4;     // cd,cs adjacent: zeroed together
    int*   cs      = (int*)p;   p += (size_t)NBUCK * 4;
    int*   offd    = (int*)p;   p += (size_t)(NBUCK + 1) * 4;
    int*   offs    = (int*)p;   p += (size_t)(NBUCK + 1) * 4;
    int*   curd    = (int*)p;   p += (size_t)NBUCK * 4;
    int*   curs    = (int*)p;   p += (size_t)NBUCK * 4;
    int*   csr     = (int*)p;   p += (size_t)e * 4;
    p = (char*)(((uintptr_t)p + 255) & ~(uintptr_t)255);
    float* bufA    = (float*)p; p += (size_t)128 * n * 4;   // xw1, then xw2
    float* bufB    = (float*)p;                              // h
    int2*  pairs   = (int2*)bufA;                            // build-phase only
    int*   bsrc    = (int*)bufB;                             // build-phase only

    zero_ints<<<(2 * NBUCK + 255) / 256, 256, 0, stream>>>(cd, 2 * NBUCK);
    coarse_hist<<<256, 256, 0, stream>>>(src, dst, cd, cs, e);
    scan_coarse<<<1, 512, 0, stream>>>(cd, cs, offd, offs, curd, curs, row_ptr, n, e);
    part_dst<<<NPART, 256, 0, stream>>>(src, dst, curd, pairs, e);
    part_src<<<NPART, 256, 0, stream>>>(src, curs, bsrc, e);
    fine_dst<<<NBUCK, 256, 0, stream>>>(offd, pairs, row_ptr, nd, csr, n);
    fine_src<<<NBUCK, 256, 0, stream>>>(offs, bsrc, ns, n);

    // layer 1: xw1 = (x @ W1) * ns ; h = relu((xw1[r]+sum nbr)*nd + b1) * ns
    gemm_mfma<128, true><<<1024, 256, 0, stream>>>(x, W1, ns, bufA, nchunks);
    agg_csr<128, true><<<n / 4, 256, 0, stream>>>(row_ptr, csr, bufA, nd, ns, b1, bufB, n);

    // layer 2: xw2 = h @ W2 ; out = (xw2[r]+sum nbr)*nd + b2
    gemm_mfma<64, false><<<1024, 256, 0, stream>>>(bufB, W2, (const float*)nullptr, bufA, nchunks);
    agg_csr<64, false><<<n / 4, 256, 0, stream>>>(row_ptr, csr, bufA, nd, ns, b2, out, n);
}

// Round 6
// 363.883 us; speedup vs baseline: 13.0876x; 1.3006x over previous
//
#include <hip/hip_runtime.h>
#include <stdint.h>

#define NN 100000
#define NE 1600000
#define NBUCK 391            // ceil(NN/256)
#define CHUNK 4000
#define NPART (NE / CHUNK)   // 400, exact

typedef __attribute__((ext_vector_type(8))) __bf16 bf16x8;
typedef __attribute__((ext_vector_type(4))) float  f32x4;
typedef unsigned int uint;

static __device__ __forceinline__ float2 bfpair(uint u) {
    union { uint i; float f; } a, b;
    a.i = (u & 0xffffu) << 16;
    b.i = u & 0xffff0000u;
    return make_float2(a.f, b.f);
}

// ---------- CSR build: two-level LDS-histogram partition (no per-edge global atomics) ----------

__global__ void zero_ints(int* p, int n) {
    int i = blockIdx.x * blockDim.x + threadIdx.x;
    if (i < n) p[i] = 0;
}

__global__ __launch_bounds__(256) void coarse_hist(const int* __restrict__ src,
        const int* __restrict__ dst, int* __restrict__ cd, int* __restrict__ cs, int e)
{
    __shared__ int hd[NBUCK], hs[NBUCK];
    for (int t = threadIdx.x; t < NBUCK; t += 256) { hd[t] = 0; hs[t] = 0; }
    __syncthreads();
    for (int i = blockIdx.x * 256 + threadIdx.x; i < e; i += gridDim.x * 256) {
        atomicAdd(&hd[dst[i] >> 8], 1);
        atomicAdd(&hs[src[i] >> 8], 1);
    }
    __syncthreads();
    for (int t = threadIdx.x; t < NBUCK; t += 256) {
        if (hd[t]) atomicAdd(&cd[t], hd[t]);
        if (hs[t]) atomicAdd(&cs[t], hs[t]);
    }
}

__global__ __launch_bounds__(512) void scan_coarse(const int* __restrict__ cd,
        const int* __restrict__ cs, int* __restrict__ offd, int* __restrict__ offs,
        int* __restrict__ curd, int* __restrict__ curs, int* __restrict__ row_ptr,
        int n, int e)
{
    __shared__ int sh[512];
    int t = threadIdx.x;
    int v = (t < NBUCK) ? cd[t] : 0;
    sh[t] = v;
    __syncthreads();
    for (int o = 1; o < 512; o <<= 1) {
        int tv = (t >= o) ? sh[t - o] : 0;
        __syncthreads();
        sh[t] += tv;
        __syncthreads();
    }
    if (t < NBUCK) { int ex = sh[t] - v; offd[t] = ex; curd[t] = ex; }
    if (t == 0) { offd[NBUCK] = e; row_ptr[n] = e; }
    __syncthreads();
    v = (t < NBUCK) ? cs[t] : 0;
    sh[t] = v;
    __syncthreads();
    for (int o = 1; o < 512; o <<= 1) {
        int tv = (t >= o) ? sh[t - o] : 0;
        __syncthreads();
        sh[t] += tv;
        __syncthreads();
    }
    if (t < NBUCK) { int ex = sh[t] - v; offs[t] = ex; curs[t] = ex; }
    if (t == 0) offs[NBUCK] = e;
}

__global__ __launch_bounds__(256) void part_dst(const int* __restrict__ src,
        const int* __restrict__ dst, int* __restrict__ curd, int2* __restrict__ pairs, int e)
{
    __shared__ int h[NBUCK];
    __shared__ int base[NBUCK];
    int beg = blockIdx.x * CHUNK;
    int end = beg + CHUNK; if (end > e) end = e;
    for (int t = threadIdx.x; t < NBUCK; t += 256) h[t] = 0;
    __syncthreads();
    for (int i = beg + threadIdx.x; i < end; i += 256)
        atomicAdd(&h[dst[i] >> 8], 1);
    __syncthreads();
    for (int t = threadIdx.x; t < NBUCK; t += 256)
        base[t] = h[t] ? atomicAdd(&curd[t], h[t]) : 0;
    __syncthreads();
    for (int i = beg + threadIdx.x; i < end; i += 256) {
        int d = dst[i];
        int pos = atomicAdd(&base[d >> 8], 1);     // LDS atomic
        pairs[pos] = make_int2(src[i], d);
    }
}

__global__ __launch_bounds__(256) void part_src(const int* __restrict__ src,
        int* __restrict__ curs, int* __restrict__ bsrc, int e)
{
    __shared__ int h[NBUCK];
    __shared__ int base[NBUCK];
    int beg = blockIdx.x * CHUNK;
    int end = beg + CHUNK; if (end > e) end = e;
    for (int t = threadIdx.x; t < NBUCK; t += 256) h[t] = 0;
    __syncthreads();
    for (int i = beg + threadIdx.x; i < end; i += 256)
        atomicAdd(&h[src[i] >> 8], 1);
    __syncthreads();
    for (int t = threadIdx.x; t < NBUCK; t += 256)
        base[t] = h[t] ? atomicAdd(&curs[t], h[t]) : 0;
    __syncthreads();
    for (int i = beg + threadIdx.x; i < end; i += 256) {
        int s = src[i];
        int pos = atomicAdd(&base[s >> 8], 1);     // LDS atomic
        bsrc[pos] = s;
    }
}

__global__ __launch_bounds__(256) void fine_dst(const int* __restrict__ offd,
        const int2* __restrict__ pairs, int* __restrict__ row_ptr,
        float* __restrict__ nd, int* __restrict__ csr, int n)
{
    __shared__ int h[256], sh[256], cur[256];
    int b = blockIdx.x;
    int beg = offd[b], end = offd[b + 1];
    int t = threadIdx.x;
    h[t] = 0;
    __syncthreads();
    for (int i = beg + t; i < end; i += 256)
        atomicAdd(&h[pairs[i].y & 255], 1);
    __syncthreads();
    int v = h[t];
    sh[t] = v;
    __syncthreads();
    for (int o = 1; o < 256; o <<= 1) {
        int tv = (t >= o) ? sh[t - o] : 0;
        __syncthreads();
        sh[t] += tv;
        __syncthreads();
    }
    int ex = sh[t] - v;
    int node = (b << 8) + t;
    if (node < n) {
        row_ptr[node] = beg + ex;
        nd[node] = rsqrtf((float)v + 1.0f);        // +1 self-loop
    }
    cur[t] = beg + ex;
    __syncthreads();
    for (int i = beg + t; i < end; i += 256) {
        int2 pr = pairs[i];
        int pos = atomicAdd(&cur[pr.y & 255], 1);  // LDS atomic
        csr[pos] = pr.x;
    }
}

__global__ __launch_bounds__(256) void fine_src(const int* __restrict__ offs,
        const int* __restrict__ bsrc, float* __restrict__ ns, int n)
{
    __shared__ int h[256];
    int b = blockIdx.x;
    int beg = offs[b], end = offs[b + 1];
    int t = threadIdx.x;
    h[t] = 0;
    __syncthreads();
    for (int i = beg + t; i < end; i += 256)
        atomicAdd(&h[bsrc[i] & 255], 1);
    __syncthreads();
    int node = (b << 8) + t;
    if (node < n) ns[node] = rsqrtf((float)h[t] + 1.0f);
}

// ---------- MFMA GEMM via split-bf16; OUTPUT IS BF16 (gather table) ----------
template<int F, bool SCALE>
__global__ __launch_bounds__(256) void gemm_mfma(const float* __restrict__ X,
        const float* __restrict__ W, const float* __restrict__ rowscale,
        __bf16* __restrict__ xw, int nchunks)
{
    __shared__ __bf16 Whi[(F/16)*4*64*8];
    __shared__ __bf16 Wlo[(F/16)*4*64*8];
    for (int idx = threadIdx.x; idx < (F/16)*4*64; idx += 256) {
        int cb = idx >> 8;
        int kc = (idx >> 6) & 3;
        int ln = idx & 63;
        int col = cb*16 + (ln & 15);
        int kb  = kc*32 + (ln >> 4)*8;
        #pragma unroll
        for (int j = 0; j < 8; ++j) {
            float f = W[(size_t)(kb + j)*F + col];
            __bf16 h = (__bf16)f;
            Whi[idx*8 + j] = h;
            Wlo[idx*8 + j] = (__bf16)(f - (float)h);
        }
    }
    __syncthreads();
    const int lane = threadIdx.x & 63;
    const int m = lane & 15, q = lane >> 4;
    int wchunk = blockIdx.x*4 + (threadIdx.x >> 6);
    int stride = gridDim.x*4;
    for (int c = wchunk; c < nchunks; c += stride) {
        int rbase = c*16;
        const float* xrow = X + (size_t)(rbase + m)*128;
        f32x4 acc[F/16];
        #pragma unroll
        for (int i = 0; i < F/16; ++i) acc[i] = (f32x4)0.f;
        #pragma unroll
        for (int kc = 0; kc < 4; ++kc) {
            int kb = kc*32 + q*8;
            float4 v0 = *(const float4*)(xrow + kb);
            float4 v1 = *(const float4*)(xrow + kb + 4);
            float xf[8] = {v0.x, v0.y, v0.z, v0.w, v1.x, v1.y, v1.z, v1.w};
            bf16x8 ahi, alo;
            #pragma unroll
            for (int j = 0; j < 8; ++j) {
                __bf16 h = (__bf16)xf[j];
                ahi[j] = h;
                alo[j] = (__bf16)(xf[j] - (float)h);
            }
            #pragma unroll
            for (int cb = 0; cb < F/16; ++cb) {
                bf16x8 bh = *(const bf16x8*)(Whi + ((cb*4 + kc)*64 + lane)*8);
                bf16x8 bl = *(const bf16x8*)(Wlo + ((cb*4 + kc)*64 + lane)*8);
                acc[cb] = __builtin_amdgcn_mfma_f32_16x16x32_bf16(ahi, bh, acc[cb], 0, 0, 0);
                acc[cb] = __builtin_amdgcn_mfma_f32_16x16x32_bf16(alo, bh, acc[cb], 0, 0, 0);
                acc[cb] = __builtin_amdgcn_mfma_f32_16x16x32_bf16(ahi, bl, acc[cb], 0, 0, 0);
            }
        }
        float s[4];
        #pragma unroll
        for (int reg = 0; reg < 4; ++reg)
            s[reg] = SCALE ? rowscale[rbase + q*4 + reg] : 1.0f;
        #pragma unroll
        for (int cb = 0; cb < F/16; ++cb)
            #pragma unroll
            for (int reg = 0; reg < 4; ++reg)
                xw[(size_t)(rbase + q*4 + reg)*F + cb*16 + m] = (__bf16)(acc[cb][reg] * s[reg]);
    }
}

// ---------- layer-1 aggregate: one wave per node, bf16 rows (128 cols = 64 uints) ----------
__global__ __launch_bounds__(256) void agg_csr128(const int* __restrict__ row_ptr,
        const int* __restrict__ csr, const uint* __restrict__ xw,
        const float* __restrict__ nd, const float* __restrict__ ns,
        const float* __restrict__ b, float* __restrict__ out, int n)
{
    int r = blockIdx.x * 4 + (threadIdx.x >> 6);
    if (r >= n) return;
    const int lane = threadIdx.x & 63;
    int beg = row_ptr[r], end = row_ptr[r + 1];
    float2 self = bfpair(xw[(size_t)r * 64 + lane]);       // self-loop
    float a0 = self.x, a1 = self.y;
    int j = beg;
    for (; j + 4 <= end; j += 4) {
        int s0 = csr[j], s1 = csr[j + 1], s2 = csr[j + 2], s3 = csr[j + 3];
        uint u0 = xw[(size_t)s0 * 64 + lane];
        uint u1 = xw[(size_t)s1 * 64 + lane];
        uint u2 = xw[(size_t)s2 * 64 + lane];
        uint u3 = xw[(size_t)s3 * 64 + lane];
        float2 f0 = bfpair(u0), f1 = bfpair(u1), f2 = bfpair(u2), f3 = bfpair(u3);
        a0 += f0.x + f1.x + f2.x + f3.x;
        a1 += f0.y + f1.y + f2.y + f3.y;
    }
    for (; j < end; ++j) {
        float2 f0 = bfpair(xw[(size_t)csr[j] * 64 + lane]);
        a0 += f0.x; a1 += f0.y;
    }
    float ndr = nd[r], nsr = ns[r];
    float o0 = fmaxf(a0 * ndr + b[2 * lane], 0.f) * nsr;
    float o1 = fmaxf(a1 * ndr + b[2 * lane + 1], 0.f) * nsr;
    ((float2*)out)[(size_t)r * 64 + lane] = make_float2(o0, o1);
}

// ---------- layer-2 aggregate: one HALF-WAVE (32 lanes) per node, bf16 rows (64 cols = 32 uints) ----------
__global__ __launch_bounds__(256) void agg_csr64(const int* __restrict__ row_ptr,
        const int* __restrict__ csr, const uint* __restrict__ xw,
        const float* __restrict__ nd, const float* __restrict__ b,
        float* __restrict__ out, int n)
{
    int r = blockIdx.x * 8 + (threadIdx.x >> 5);
    if (r >= n) return;
    const int lane = threadIdx.x & 31;
    int beg = row_ptr[r], end = row_ptr[r + 1];
    float2 self = bfpair(xw[(size_t)r * 32 + lane]);       // self-loop
    float a0 = self.x, a1 = self.y;
    int j = beg;
    for (; j + 4 <= end; j += 4) {
        int s0 = csr[j], s1 = csr[j + 1], s2 = csr[j + 2], s3 = csr[j + 3];
        uint u0 = xw[(size_t)s0 * 32 + lane];
        uint u1 = xw[(size_t)s1 * 32 + lane];
        uint u2 = xw[(size_t)s2 * 32 + lane];
        uint u3 = xw[(size_t)s3 * 32 + lane];
        float2 f0 = bfpair(u0), f1 = bfpair(u1), f2 = bfpair(u2), f3 = bfpair(u3);
        a0 += f0.x + f1.x + f2.x + f3.x;
        a1 += f0.y + f1.y + f2.y + f3.y;
    }
    for (; j < end; ++j) {
        float2 f0 = bfpair(xw[(size_t)csr[j] * 32 + lane]);
        a0 += f0.x; a1 += f0.y;
    }
    float ndr = nd[r];
    float o0 = a0 * ndr + b[2 * lane];
    float o1 = a1 * ndr + b[2 * lane + 1];
    ((float2*)out)[(size_t)r * 32 + lane] = make_float2(o0, o1);
}

extern "C" void kernel_launch(void* const* d_in, const int* in_sizes, int n_in,
                              void* d_out, int out_size, void* d_ws, size_t ws_size,
                              hipStream_t stream)
{
    const float* x  = (const float*)d_in[0];   // [N,128] f32
    const int* src  = (const int*)d_in[1];     // [E]
    const int* dst  = (const int*)d_in[2];     // [E]
    const float* W1 = (const float*)d_in[3];   // [128,128] f32
    const float* b1 = (const float*)d_in[4];   // [128] f32
    const float* W2 = (const float*)d_in[5];   // [128,64] f32
    const float* b2 = (const float*)d_in[6];   // [64] f32
    float* out = (float*)d_out;                // [N,64] f32

    const int n = NN, e = NE;
    const int nchunks = n / 16;                // 6250, exact

    // workspace layout
    char* p = (char*)d_ws;
    float* ns      = (float*)p; p += (size_t)n * 4;
    float* nd      = (float*)p; p += (size_t)n * 4;
    int*   row_ptr = (int*)p;   p += (size_t)(n + 1) * 4;
    int*   cd      = (int*)p;   p += (size_t)NBUCK * 4;     // cd,cs adjacent: zeroed together
    int*   cs      = (int*)p;   p += (size_t)NBUCK * 4;
    int*   offd    = (int*)p;   p += (size_t)(NBUCK + 1) * 4;
    int*   offs    = (int*)p;   p += (size_t)(NBUCK + 1) * 4;
    int*   curd    = (int*)p;   p += (size_t)NBUCK * 4;
    int*   curs    = (int*)p;   p += (size_t)NBUCK * 4;
    int*   csr     = (int*)p;   p += (size_t)e * 4;
    p = (char*)(((uintptr_t)p + 255) & ~(uintptr_t)255);
    __bf16* bufA   = (__bf16*)p; p += (size_t)128 * n * 2;  // xw1 bf16, then xw2 bf16
    p = (char*)(((uintptr_t)p + 255) & ~(uintptr_t)255);
    float* bufB    = (float*)p;                              // h f32 [N,128]
    int2*  pairs   = (int2*)bufB;                            // build-phase only (12.8 MB < 51.2 MB)
    int*   bsrc    = (int*)bufA;                             // build-phase only (6.4 MB < 25.6 MB)

    zero_ints<<<(2 * NBUCK + 255) / 256, 256, 0, stream>>>(cd, 2 * NBUCK);
    coarse_hist<<<256, 256, 0, stream>>>(src, dst, cd, cs, e);
    scan_coarse<<<1, 512, 0, stream>>>(cd, cs, offd, offs, curd, curs, row_ptr, n, e);
    part_dst<<<NPART, 256, 0, stream>>>(src, dst, curd, pairs, e);
    part_src<<<NPART, 256, 0, stream>>>(src, curs, bsrc, e);
    fine_dst<<<NBUCK, 256, 0, stream>>>(offd, pairs, row_ptr, nd, csr, n);
    fine_src<<<NBUCK, 256, 0, stream>>>(offs, bsrc, ns, n);

    // layer 1: xw1 = bf16((x @ W1) * ns) ; h = relu((xw1[r]+sum nbr)*nd + b1) * ns  (f32)
    gemm_mfma<128, true><<<1024, 256, 0, stream>>>(x, W1, ns, bufA, nchunks);
    agg_csr128<<<n / 4, 256, 0, stream>>>(row_ptr, csr, (const uint*)bufA, nd, ns, b1, bufB, n);

    // layer 2: xw2 = bf16(h @ W2) ; out = (xw2[r]+sum nbr)*nd + b2
    gemm_mfma<64, false><<<1024, 256, 0, stream>>>(bufB, W2, (const float*)nullptr, bufA, nchunks);
    agg_csr64<<<n / 8, 256, 0, stream>>>(row_ptr, csr, (const uint*)bufA, nd, b2, out, n);
}

// Round 7
// 346.250 us; speedup vs baseline: 13.7542x; 1.0509x over previous
//
#include <hip/hip_runtime.h>
#include <stdint.h>

#define NN 100000
#define NE 1600000
#define NBUCK 391            // ceil(NN/256)
#define CHUNK 4000
#define NPART (NE / CHUNK)   // 400, exact

typedef __attribute__((ext_vector_type(8))) __bf16 bf16x8;
typedef __attribute__((ext_vector_type(4))) float  f32x4;
typedef unsigned int uint;

static __device__ __forceinline__ float blo(uint u) {
    union { uint i; float f; } v; v.i = u << 16; return v.f;
}
static __device__ __forceinline__ float bhi(uint u) {
    union { uint i; float f; } v; v.i = u & 0xffff0000u; return v.f;
}

// ---------- CSR build: two-level LDS-histogram partition (no per-edge global atomics) ----------

__global__ void zero_ints(int* p, int n) {
    int i = blockIdx.x * blockDim.x + threadIdx.x;
    if (i < n) p[i] = 0;
}

__global__ __launch_bounds__(256) void coarse_hist(const int* __restrict__ src,
        const int* __restrict__ dst, int* __restrict__ cd, int* __restrict__ cs, int e)
{
    __shared__ int hd[NBUCK], hs[NBUCK];
    for (int t = threadIdx.x; t < NBUCK; t += 256) { hd[t] = 0; hs[t] = 0; }
    __syncthreads();
    for (int i = blockIdx.x * 256 + threadIdx.x; i < e; i += gridDim.x * 256) {
        atomicAdd(&hd[dst[i] >> 8], 1);
        atomicAdd(&hs[src[i] >> 8], 1);
    }
    __syncthreads();
    for (int t = threadIdx.x; t < NBUCK; t += 256) {
        if (hd[t]) atomicAdd(&cd[t], hd[t]);
        if (hs[t]) atomicAdd(&cs[t], hs[t]);
    }
}

__global__ __launch_bounds__(512) void scan_coarse(const int* __restrict__ cd,
        const int* __restrict__ cs, int* __restrict__ offd, int* __restrict__ offs,
        int* __restrict__ curd, int* __restrict__ curs, int* __restrict__ row_ptr,
        int n, int e)
{
    __shared__ int sh[512];
    int t = threadIdx.x;
    int v = (t < NBUCK) ? cd[t] : 0;
    sh[t] = v;
    __syncthreads();
    for (int o = 1; o < 512; o <<= 1) {
        int tv = (t >= o) ? sh[t - o] : 0;
        __syncthreads();
        sh[t] += tv;
        __syncthreads();
    }
    if (t < NBUCK) { int ex = sh[t] - v; offd[t] = ex; curd[t] = ex; }
    if (t == 0) { offd[NBUCK] = e; row_ptr[n] = e; }
    __syncthreads();
    v = (t < NBUCK) ? cs[t] : 0;
    sh[t] = v;
    __syncthreads();
    for (int o = 1; o < 512; o <<= 1) {
        int tv = (t >= o) ? sh[t - o] : 0;
        __syncthreads();
        sh[t] += tv;
        __syncthreads();
    }
    if (t < NBUCK) { int ex = sh[t] - v; offs[t] = ex; curs[t] = ex; }
    if (t == 0) offs[NBUCK] = e;
}

// partition edges by dst>>8 (pairs) AND src values by src>>8 (bsrc), one pass
__global__ __launch_bounds__(256) void part_both(const int* __restrict__ src,
        const int* __restrict__ dst, int* __restrict__ curd, int* __restrict__ curs,
        int2* __restrict__ pairs, int* __restrict__ bsrc, int e)
{
    __shared__ int hd[NBUCK], hs[NBUCK], based[NBUCK], bases[NBUCK];
    int beg = blockIdx.x * CHUNK;
    int end = beg + CHUNK; if (end > e) end = e;
    for (int t = threadIdx.x; t < NBUCK; t += 256) { hd[t] = 0; hs[t] = 0; }
    __syncthreads();
    for (int i = beg + threadIdx.x; i < end; i += 256) {
        atomicAdd(&hd[dst[i] >> 8], 1);
        atomicAdd(&hs[src[i] >> 8], 1);
    }
    __syncthreads();
    for (int t = threadIdx.x; t < NBUCK; t += 256) {
        based[t] = hd[t] ? atomicAdd(&curd[t], hd[t]) : 0;
        bases[t] = hs[t] ? atomicAdd(&curs[t], hs[t]) : 0;
    }
    __syncthreads();
    for (int i = beg + threadIdx.x; i < end; i += 256) {
        int s = src[i], d = dst[i];
        int pd = atomicAdd(&based[d >> 8], 1);     // LDS atomic
        pairs[pd] = make_int2(s, d);
        int ps = atomicAdd(&bases[s >> 8], 1);     // LDS atomic
        bsrc[ps] = s;
    }
}

// one block per bucket: dst phase (row_ptr, nd, CSR placement) then src phase (ns)
__global__ __launch_bounds__(256) void fine_both(const int* __restrict__ offd,
        const int2* __restrict__ pairs, const int* __restrict__ offs,
        const int* __restrict__ bsrc, int* __restrict__ row_ptr,
        float* __restrict__ nd, float* __restrict__ ns, int* __restrict__ csr, int n)
{
    __shared__ int h[256], sh[256], cur[256];
    int b = blockIdx.x;
    int t = threadIdx.x;
    int node = (b << 8) + t;
    // ---- dst phase ----
    int beg = offd[b], end = offd[b + 1];
    h[t] = 0;
    __syncthreads();
    for (int i = beg + t; i < end; i += 256)
        atomicAdd(&h[pairs[i].y & 255], 1);
    __syncthreads();
    int v = h[t];
    sh[t] = v;
    __syncthreads();
    for (int o = 1; o < 256; o <<= 1) {
        int tv = (t >= o) ? sh[t - o] : 0;
        __syncthreads();
        sh[t] += tv;
        __syncthreads();
    }
    int ex = sh[t] - v;
    if (node < n) {
        row_ptr[node] = beg + ex;
        nd[node] = rsqrtf((float)v + 1.0f);        // +1 self-loop
    }
    cur[t] = beg + ex;
    __syncthreads();
    for (int i = beg + t; i < end; i += 256) {
        int2 pr = pairs[i];
        int pos = atomicAdd(&cur[pr.y & 255], 1);  // LDS atomic
        csr[pos] = pr.x;
    }
    // ---- src phase (h reuse safe: dst scatter only touches cur/global) ----
    h[t] = 0;
    __syncthreads();
    int sbeg = offs[b], send = offs[b + 1];
    for (int i = sbeg + t; i < send; i += 256)
        atomicAdd(&h[bsrc[i] & 255], 1);
    __syncthreads();
    if (node < n) ns[node] = rsqrtf((float)h[t] + 1.0f);
}

// ---------- MFMA GEMM via split-bf16; OUTPUT IS BF16 (gather table) ----------
// grid = ceil(nchunks/4) blocks; exactly one 16-row chunk per wave.
template<int F, bool SCALE>
__global__ __launch_bounds__(256) void gemm_mfma(const float* __restrict__ X,
        const float* __restrict__ W, const float* __restrict__ rowscale,
        __bf16* __restrict__ xw, int nchunks)
{
    __shared__ __bf16 Whi[(F/16)*4*64*8];
    __shared__ __bf16 Wlo[(F/16)*4*64*8];
    for (int idx = threadIdx.x; idx < (F/16)*4*64; idx += 256) {
        int cb = idx >> 8;
        int kc = (idx >> 6) & 3;
        int ln = idx & 63;
        int col = cb*16 + (ln & 15);
        int kb  = kc*32 + (ln >> 4)*8;
        #pragma unroll
        for (int j = 0; j < 8; ++j) {
            float f = W[(size_t)(kb + j)*F + col];
            __bf16 h = (__bf16)f;
            Whi[idx*8 + j] = h;
            Wlo[idx*8 + j] = (__bf16)(f - (float)h);
        }
    }
    __syncthreads();
    const int lane = threadIdx.x & 63;
    const int m = lane & 15, q = lane >> 4;
    int c = blockIdx.x*4 + (threadIdx.x >> 6);
    if (c >= nchunks) return;
    int rbase = c*16;
    const float* xrow = X + (size_t)(rbase + m)*128;
    f32x4 acc[F/16];
    #pragma unroll
    for (int i = 0; i < F/16; ++i) acc[i] = (f32x4)0.f;
    #pragma unroll
    for (int kc = 0; kc < 4; ++kc) {
        int kb = kc*32 + q*8;
        float4 v0 = *(const float4*)(xrow + kb);
        float4 v1 = *(const float4*)(xrow + kb + 4);
        float xf[8] = {v0.x, v0.y, v0.z, v0.w, v1.x, v1.y, v1.z, v1.w};
        bf16x8 ahi, alo;
        #pragma unroll
        for (int j = 0; j < 8; ++j) {
            __bf16 h = (__bf16)xf[j];
            ahi[j] = h;
            alo[j] = (__bf16)(xf[j] - (float)h);
        }
        #pragma unroll
        for (int cb = 0; cb < F/16; ++cb) {
            bf16x8 bh = *(const bf16x8*)(Whi + ((cb*4 + kc)*64 + lane)*8);
            bf16x8 bl = *(const bf16x8*)(Wlo + ((cb*4 + kc)*64 + lane)*8);
            acc[cb] = __builtin_amdgcn_mfma_f32_16x16x32_bf16(ahi, bh, acc[cb], 0, 0, 0);
            acc[cb] = __builtin_amdgcn_mfma_f32_16x16x32_bf16(alo, bh, acc[cb], 0, 0, 0);
            acc[cb] = __builtin_amdgcn_mfma_f32_16x16x32_bf16(ahi, bl, acc[cb], 0, 0, 0);
        }
    }
    float s[4];
    #pragma unroll
    for (int reg = 0; reg < 4; ++reg)
        s[reg] = SCALE ? rowscale[rbase + q*4 + reg] : 1.0f;
    #pragma unroll
    for (int cb = 0; cb < F/16; ++cb)
        #pragma unroll
        for (int reg = 0; reg < 4; ++reg)
            xw[(size_t)(rbase + q*4 + reg)*F + cb*16 + m] = (__bf16)(acc[cb][reg] * s[reg]);
}

// ---------- layer-1 aggregate: one wave per node, quarter-wave (16 lanes x uint4) per edge row ----------
__global__ __launch_bounds__(256) void agg_csr128(const int* __restrict__ row_ptr,
        const int* __restrict__ csr, const uint4* __restrict__ xw,
        const float* __restrict__ nd, const float* __restrict__ ns,
        const float* __restrict__ b, float* __restrict__ out, int n)
{
    int r = blockIdx.x * 4 + (threadIdx.x >> 6);
    if (r >= n) return;
    const int lane = threadIdx.x & 63;
    const int q = lane >> 4, ql = lane & 15;
    int beg = row_ptr[r], end = row_ptr[r + 1];
    float a[8];
    if (q == 0) {                                   // self-loop row, quarter 0 only
        uint4 u = xw[(size_t)r * 16 + ql];
        a[0]=blo(u.x); a[1]=bhi(u.x); a[2]=blo(u.y); a[3]=bhi(u.y);
        a[4]=blo(u.z); a[5]=bhi(u.z); a[6]=blo(u.w); a[7]=bhi(u.w);
    } else {
        #pragma unroll
        for (int i = 0; i < 8; ++i) a[i] = 0.f;
    }
    int j = beg;
    for (; j + 16 <= end; j += 16) {                // 16 edges: 4 uint4 loads/lane in flight
        int s0 = csr[j + q], s1 = csr[j + 4 + q], s2 = csr[j + 8 + q], s3 = csr[j + 12 + q];
        uint4 u0 = xw[(size_t)s0 * 16 + ql];
        uint4 u1 = xw[(size_t)s1 * 16 + ql];
        uint4 u2 = xw[(size_t)s2 * 16 + ql];
        uint4 u3 = xw[(size_t)s3 * 16 + ql];
        a[0]+=blo(u0.x)+blo(u1.x)+blo(u2.x)+blo(u3.x); a[1]+=bhi(u0.x)+bhi(u1.x)+bhi(u2.x)+bhi(u3.x);
        a[2]+=blo(u0.y)+blo(u1.y)+blo(u2.y)+blo(u3.y); a[3]+=bhi(u0.y)+bhi(u1.y)+bhi(u2.y)+bhi(u3.y);
        a[4]+=blo(u0.z)+blo(u1.z)+blo(u2.z)+blo(u3.z); a[5]+=bhi(u0.z)+bhi(u1.z)+bhi(u2.z)+bhi(u3.z);
        a[6]+=blo(u0.w)+blo(u1.w)+blo(u2.w)+blo(u3.w); a[7]+=bhi(u0.w)+bhi(u1.w)+bhi(u2.w)+bhi(u3.w);
    }
    for (; j + 4 <= end; j += 4) {
        int s0 = csr[j + q];
        uint4 u0 = xw[(size_t)s0 * 16 + ql];
        a[0]+=blo(u0.x); a[1]+=bhi(u0.x); a[2]+=blo(u0.y); a[3]+=bhi(u0.y);
        a[4]+=blo(u0.z); a[5]+=bhi(u0.z); a[6]+=blo(u0.w); a[7]+=bhi(u0.w);
    }
    int rem = end - j;                              // 0..3
    if (q < rem) {
        int s0 = csr[j + q];
        uint4 u0 = xw[(size_t)s0 * 16 + ql];
        a[0]+=blo(u0.x); a[1]+=bhi(u0.x); a[2]+=blo(u0.y); a[3]+=bhi(u0.y);
        a[4]+=blo(u0.z); a[5]+=bhi(u0.z); a[6]+=blo(u0.w); a[7]+=bhi(u0.w);
    }
    #pragma unroll
    for (int i = 0; i < 8; ++i) {
        a[i] += __shfl_xor(a[i], 32);
        a[i] += __shfl_xor(a[i], 16);
    }
    if (q == 0) {
        float ndr = nd[r], nsr = ns[r];
        float4 b0 = *(const float4*)(b + ql * 8);
        float4 b1 = *(const float4*)(b + ql * 8 + 4);
        float4 o0, o1;
        o0.x = fmaxf(a[0]*ndr + b0.x, 0.f) * nsr;
        o0.y = fmaxf(a[1]*ndr + b0.y, 0.f) * nsr;
        o0.z = fmaxf(a[2]*ndr + b0.z, 0.f) * nsr;
        o0.w = fmaxf(a[3]*ndr + b0.w, 0.f) * nsr;
        o1.x = fmaxf(a[4]*ndr + b1.x, 0.f) * nsr;
        o1.y = fmaxf(a[5]*ndr + b1.y, 0.f) * nsr;
        o1.z = fmaxf(a[6]*ndr + b1.z, 0.f) * nsr;
        o1.w = fmaxf(a[7]*ndr + b1.w, 0.f) * nsr;
        *(float4*)(out + (size_t)r * 128 + ql * 8)     = o0;
        *(float4*)(out + (size_t)r * 128 + ql * 8 + 4) = o1;
    }
}

// ---------- layer-2 aggregate: one wave per node, quarter-wave (16 lanes x uint2) per edge row ----------
__global__ __launch_bounds__(256) void agg_csr64(const int* __restrict__ row_ptr,
        const int* __restrict__ csr, const uint2* __restrict__ xw,
        const float* __restrict__ nd, const float* __restrict__ b,
        float* __restrict__ out, int n)
{
    int r = blockIdx.x * 4 + (threadIdx.x >> 6);
    if (r >= n) return;
    const int lane = threadIdx.x & 63;
    const int q = lane >> 4, ql = lane & 15;
    int beg = row_ptr[r], end = row_ptr[r + 1];
    float a[4];
    if (q == 0) {                                   // self-loop row
        uint2 u = xw[(size_t)r * 16 + ql];
        a[0]=blo(u.x); a[1]=bhi(u.x); a[2]=blo(u.y); a[3]=bhi(u.y);
    } else {
        #pragma unroll
        for (int i = 0; i < 4; ++i) a[i] = 0.f;
    }
    int j = beg;
    for (; j + 16 <= end; j += 16) {
        int s0 = csr[j + q], s1 = csr[j + 4 + q], s2 = csr[j + 8 + q], s3 = csr[j + 12 + q];
        uint2 u0 = xw[(size_t)s0 * 16 + ql];
        uint2 u1 = xw[(size_t)s1 * 16 + ql];
        uint2 u2 = xw[(size_t)s2 * 16 + ql];
        uint2 u3 = xw[(size_t)s3 * 16 + ql];
        a[0]+=blo(u0.x)+blo(u1.x)+blo(u2.x)+blo(u3.x); a[1]+=bhi(u0.x)+bhi(u1.x)+bhi(u2.x)+bhi(u3.x);
        a[2]+=blo(u0.y)+blo(u1.y)+blo(u2.y)+blo(u3.y); a[3]+=bhi(u0.y)+bhi(u1.y)+bhi(u2.y)+bhi(u3.y);
    }
    for (; j + 4 <= end; j += 4) {
        int s0 = csr[j + q];
        uint2 u0 = xw[(size_t)s0 * 16 + ql];
        a[0]+=blo(u0.x); a[1]+=bhi(u0.x); a[2]+=blo(u0.y); a[3]+=bhi(u0.y);
    }
    int rem = end - j;
    if (q < rem) {
        int s0 = csr[j + q];
        uint2 u0 = xw[(size_t)s0 * 16 + ql];
        a[0]+=blo(u0.x); a[1]+=bhi(u0.x); a[2]+=blo(u0.y); a[3]+=bhi(u0.y);
    }
    #pragma unroll
    for (int i = 0; i < 4; ++i) {
        a[i] += __shfl_xor(a[i], 32);
        a[i] += __shfl_xor(a[i], 16);
    }
    if (q == 0) {
        float ndr = nd[r];
        float4 bb = *(const float4*)(b + ql * 4);
        float4 o;
        o.x = a[0]*ndr + bb.x;
        o.y = a[1]*ndr + bb.y;
        o.z = a[2]*ndr + bb.z;
        o.w = a[3]*ndr + bb.w;
        *(float4*)(out + (size_t)r * 64 + ql * 4) = o;
    }
}

extern "C" void kernel_launch(void* const* d_in, const int* in_sizes, int n_in,
                              void* d_out, int out_size, void* d_ws, size_t ws_size,
                              hipStream_t stream)
{
    const float* x  = (const float*)d_in[0];   // [N,128] f32
    const int* src  = (const int*)d_in[1];     // [E]
    const int* dst  = (const int*)d_in[2];     // [E]
    const float* W1 = (const float*)d_in[3];   // [128,128] f32
    const float* b1 = (const float*)d_in[4];   // [128] f32
    const float* W2 = (const float*)d_in[5];   // [128,64] f32
    const float* b2 = (const float*)d_in[6];   // [64] f32
    float* out = (float*)d_out;                // [N,64] f32

    const int n = NN, e = NE;
    const int nchunks = n / 16;                // 6250, exact
    const int gemm_grid = (nchunks + 3) / 4;   // 1563: one chunk per wave

    // workspace layout
    char* p = (char*)d_ws;
    float* ns      = (float*)p; p += (size_t)n * 4;
    float* nd      = (float*)p; p += (size_t)n * 4;
    int*   row_ptr = (int*)p;   p += (size_t)(n + 1) * 4;
    int*   cd      = (int*)p;   p += (size_t)NBUCK * 4;     // cd,cs adjacent: zeroed together
    int*   cs      = (int*)p;   p += (size_t)NBUCK * 4;
    int*   offd    = (int*)p;   p += (size_t)(NBUCK + 1) * 4;
    int*   offs    = (int*)p;   p += (size_t)(NBUCK + 1) * 4;
    int*   curd    = (int*)p;   p += (size_t)NBUCK * 4;
    int*   curs    = (int*)p;   p += (size_t)NBUCK * 4;
    int*   csr     = (int*)p;   p += (size_t)e * 4;
    p = (char*)(((uintptr_t)p + 255) & ~(uintptr_t)255);
    __bf16* bufA   = (__bf16*)p; p += (size_t)128 * n * 2;  // xw1 bf16, then xw2 bf16
    p = (char*)(((uintptr_t)p + 255) & ~(uintptr_t)255);
    float* bufB    = (float*)p;                              // h f32 [N,128]
    int2*  pairs   = (int2*)bufB;                            // build-phase only
    int*   bsrc    = (int*)bufA;                             // build-phase only

    zero_ints<<<(2 * NBUCK + 255) / 256, 256, 0, stream>>>(cd, 2 * NBUCK);
    coarse_hist<<<256, 256, 0, stream>>>(src, dst, cd, cs, e);
    scan_coarse<<<1, 512, 0, stream>>>(cd, cs, offd, offs, curd, curs, row_ptr, n, e);
    part_both<<<NPART, 256, 0, stream>>>(src, dst, curd, curs, pairs, bsrc, e);
    fine_both<<<NBUCK, 256, 0, stream>>>(offd, pairs, offs, bsrc, row_ptr, nd, ns, csr, n);

    // layer 1: xw1 = bf16((x @ W1) * ns) ; h = relu((xw1[r]+sum nbr)*nd + b1) * ns  (f32)
    gemm_mfma<128, true><<<gemm_grid, 256, 0, stream>>>(x, W1, ns, bufA, nchunks);
    agg_csr128<<<(n + 3) / 4, 256, 0, stream>>>(row_ptr, csr, (const uint4*)bufA, nd, ns, b1, bufB, n);

    // layer 2: xw2 = bf16(h @ W2) ; out = (xw2[r]+sum nbr)*nd + b2
    gemm_mfma<64, false><<<gemm_grid, 256, 0, stream>>>(bufB, W2, (const float*)nullptr, bufA, nchunks);
    agg_csr64<<<(n + 3) / 4, 256, 0, stream>>>(row_ptr, csr, (const uint2*)bufA, nd, b2, out, n);
}